// Round 11
// baseline (280.049 us; speedup 1.0000x reference)
//
#include <hip/hip_runtime.h>

#define DIM 64
#define LN_EPS 1e-5f
#define XS_STRIDE 68
#define RPB 4    // rows per block (one row per wave)

// ---------------- CSR build (once per call) ----------------

__global__ void k_zero(int* __restrict__ deg, int* __restrict__ counter, int n) {
    int i = blockIdx.x * blockDim.x + threadIdx.x;
    if (i < n) deg[i] = 0;
    if (i == 0) { counter[0] = 0; counter[1] = 0; }
}

// rank trick: the degree-count atomic ALREADY returns each edge's unique
// slot within its destination row. Save it; k_fill then needs no atomics.
__global__ void k_count(const int* __restrict__ dst, int* __restrict__ deg,
                        int* __restrict__ rank, int e_cnt) {
    int e = blockIdx.x * blockDim.x + threadIdx.x;
    if (e < e_cnt) rank[e] = atomicAdd(&deg[dst[e]], 1);
}

__global__ void k_reserve(const int* __restrict__ deg, int* __restrict__ rowstart,
                          float* __restrict__ dinv,
                          int* __restrict__ counter, int n) {
    int i = blockIdx.x * blockDim.x + threadIdx.x;
    if (i >= n) return;
    int d = deg[i];
    int s = atomicAdd(counter, d);
    rowstart[i] = s;
    dinv[i] = rsqrtf((float)(d + 1));
}

// atomic-free scatter: pos = rowstart[dst] + rank (unique, in-range)
__global__ void k_fill(const int* __restrict__ src, const int* __restrict__ dst,
                       const float* __restrict__ dinv,
                       const int* __restrict__ rowstart,
                       const int* __restrict__ rank,
                       int2* __restrict__ csr, int e_cnt) {
    int e = blockIdx.x * blockDim.x + threadIdx.x;
    if (e >= e_cnt) return;
    int s = src[e], d = dst[e];
    int pos = rowstart[d] + rank[e];
    float w = dinv[s] * dinv[d];
    csr[pos] = make_int2(s, __float_as_int(w));
}

// ---------------- fused per-layer kernel ----------------
// EDGE-SLOT PARALLEL (round-11): one row per WAVE; lane = (es = lane>>4,
// fq = lane&15). Per iteration the wave covers 16 edges (4 slots x 4-deep
// unroll) using the same 4x(int2+float4) in-flight registers per lane as the
// verified round-9 structure -> no new spill risk (rounds 7-8 lesson: VGPR
// pressure, not occupancy, is the cliff). Typical row (deg~16) completes in
// ONE batch instead of ~4 serial ones. Slot partials fold with shfl_xor
// (16/32); es==0 adds self-loop pre-fold. Phase 2 splits the kc loop across
// es (4x fewer iterations/lane) and folds the same way.
// RPB=4 -> grid 12500 blocks, LDS 17.1 KB -> 8 blocks/CU = 32 waves/CU
// (100% ceiling). Occupancy from MORE blocks, not fatter blocks.
// RACE NOTE: xin and out must NOT alias within one dispatch — the gather
// reads arbitrary rows of xin while this block writes its own rows of out.
// kernel_launch ping-pongs layer outputs (out / bufA) to guarantee this.
__global__ __launch_bounds__(256) void k_layer(const int* __restrict__ rowstart,
                                               const int* __restrict__ deg,
                                               const float* __restrict__ dinv,
                                               const int2* __restrict__ csr,
                                               const float* __restrict__ xin,
                                               const float* __restrict__ W,
                                               const float* __restrict__ b,
                                               const float* __restrict__ gamma,
                                               const float* __restrict__ beta,
                                               float* __restrict__ out, int n) {
    __shared__ float ws[DIM * DIM];
    __shared__ float xs[RPB * XS_STRIDE];
    int t = threadIdx.x;
    int base = blockIdx.x * RPB;

    {   // stage W: 1024 float4 across 256 threads; issued first so the loads
        // overlap aggregation latency. (16 KB x 12500 blocks = 200 MB of
        // L2-resident broadcast reads ~ 6 us/layer, overlapped.)
        const float4* W4 = (const float4*)W;
        float4* ws4 = (float4*)ws;
#pragma unroll
        for (int i = 0; i < 4; i++) ws4[t + 256 * i] = W4[t + 256 * i];
    }

    // ---- phase 1: aggregation (edge-slot parallel) ----
    int wave = t >> 6, lane = t & 63;
    int es = lane >> 4;    // edge slot 0..3
    int fq = lane & 15;    // feature quad 0..15 (float4 each)
    int row = base + wave; // one row per wave
    const float4* xin4 = (const float4*)xin;

    float4 acc = make_float4(0.f, 0.f, 0.f, 0.f);
    if (row < n) {
        int s0 = rowstart[row];
        int cnt = deg[row];
        int i = 0;
        // 16 edges per iteration: slot es takes edges i+4u+es, u=0..3
        for (; i + 16 <= cnt; i += 16) {
            int2 e0 = csr[s0 + i + es];
            int2 e1 = csr[s0 + i + 4 + es];
            int2 e2 = csr[s0 + i + 8 + es];
            int2 e3 = csr[s0 + i + 12 + es];
            float4 h0 = xin4[(size_t)e0.x * 16 + fq];
            float4 h1 = xin4[(size_t)e1.x * 16 + fq];
            float4 h2 = xin4[(size_t)e2.x * 16 + fq];
            float4 h3 = xin4[(size_t)e3.x * 16 + fq];
            float w0 = __int_as_float(e0.y);
            float w1 = __int_as_float(e1.y);
            float w2 = __int_as_float(e2.y);
            float w3 = __int_as_float(e3.y);
            acc.x = fmaf(w0, h0.x, acc.x);
            acc.y = fmaf(w0, h0.y, acc.y);
            acc.z = fmaf(w0, h0.z, acc.z);
            acc.w = fmaf(w0, h0.w, acc.w);
            acc.x = fmaf(w1, h1.x, acc.x);
            acc.y = fmaf(w1, h1.y, acc.y);
            acc.z = fmaf(w1, h1.z, acc.z);
            acc.w = fmaf(w1, h1.w, acc.w);
            acc.x = fmaf(w2, h2.x, acc.x);
            acc.y = fmaf(w2, h2.y, acc.y);
            acc.z = fmaf(w2, h2.z, acc.z);
            acc.w = fmaf(w2, h2.w, acc.w);
            acc.x = fmaf(w3, h3.x, acc.x);
            acc.y = fmaf(w3, h3.y, acc.y);
            acc.z = fmaf(w3, h3.z, acc.z);
            acc.w = fmaf(w3, h3.w, acc.w);
        }
        // tail: up to 15 edges, 4 independent guarded groups (ILP kept)
#pragma unroll
        for (int u = 0; u < 4; u++) {
            int idx = i + 4 * u + es;
            if (idx < cnt) {
                int2 e0 = csr[s0 + idx];
                float4 h0 = xin4[(size_t)e0.x * 16 + fq];
                float w0 = __int_as_float(e0.y);
                acc.x = fmaf(w0, h0.x, acc.x);
                acc.y = fmaf(w0, h0.y, acc.y);
                acc.z = fmaf(w0, h0.z, acc.z);
                acc.w = fmaf(w0, h0.w, acc.w);
            }
        }
        // self-loop (added once, pre-fold): dinv^2 * x[row]
        if (es == 0) {
            float di = dinv[row];
            float w = di * di;
            float4 xv = xin4[(size_t)row * 16 + fq];
            acc.x = fmaf(w, xv.x, acc.x);
            acc.y = fmaf(w, xv.y, acc.y);
            acc.z = fmaf(w, xv.z, acc.z);
            acc.w = fmaf(w, xv.w, acc.w);
        }
    }
    // fold the 4 edge slots (butterfly keeps all lanes valid)
    acc.x += __shfl_xor(acc.x, 16, 64);
    acc.y += __shfl_xor(acc.y, 16, 64);
    acc.z += __shfl_xor(acc.z, 16, 64);
    acc.w += __shfl_xor(acc.w, 16, 64);
    acc.x += __shfl_xor(acc.x, 32, 64);
    acc.y += __shfl_xor(acc.y, 32, 64);
    acc.z += __shfl_xor(acc.z, 32, 64);
    acc.w += __shfl_xor(acc.w, 32, 64);
    if (es == 0)
        *(float4*)(xs + wave * XS_STRIDE + fq * 4) = acc;
    __syncthreads();   // covers ws (cross-wave) and xs (wave-local)

    // ---- phase 2: GEMM (kc split across es) + bias + LN + relu ----
    float4 a2 = make_float4(0.f, 0.f, 0.f, 0.f);
#pragma unroll
    for (int u = 0; u < 4; u++) {
        int kc = es * 4 + u;
        float4 xv = *(const float4*)(xs + wave * XS_STRIDE + kc * 4);
        float4 w0 = *(const float4*)(ws + (4 * kc + 0) * DIM + fq * 4);
        float4 w1 = *(const float4*)(ws + (4 * kc + 1) * DIM + fq * 4);
        float4 w2 = *(const float4*)(ws + (4 * kc + 2) * DIM + fq * 4);
        float4 w3 = *(const float4*)(ws + (4 * kc + 3) * DIM + fq * 4);
        a2.x = fmaf(xv.x, w0.x, a2.x);
        a2.y = fmaf(xv.x, w0.y, a2.y);
        a2.z = fmaf(xv.x, w0.z, a2.z);
        a2.w = fmaf(xv.x, w0.w, a2.w);
        a2.x = fmaf(xv.y, w1.x, a2.x);
        a2.y = fmaf(xv.y, w1.y, a2.y);
        a2.z = fmaf(xv.y, w1.z, a2.z);
        a2.w = fmaf(xv.y, w1.w, a2.w);
        a2.x = fmaf(xv.z, w2.x, a2.x);
        a2.y = fmaf(xv.z, w2.y, a2.y);
        a2.z = fmaf(xv.z, w2.z, a2.z);
        a2.w = fmaf(xv.z, w2.w, a2.w);
        a2.x = fmaf(xv.w, w3.x, a2.x);
        a2.y = fmaf(xv.w, w3.y, a2.y);
        a2.z = fmaf(xv.w, w3.z, a2.z);
        a2.w = fmaf(xv.w, w3.w, a2.w);
    }
    // fold kc partials across es
    a2.x += __shfl_xor(a2.x, 16, 64);
    a2.y += __shfl_xor(a2.y, 16, 64);
    a2.z += __shfl_xor(a2.z, 16, 64);
    a2.w += __shfl_xor(a2.w, 16, 64);
    a2.x += __shfl_xor(a2.x, 32, 64);
    a2.y += __shfl_xor(a2.y, 32, 64);
    a2.z += __shfl_xor(a2.z, 32, 64);
    a2.w += __shfl_xor(a2.w, 32, 64);

    float4 b4 = *(const float4*)(b + fq * 4);
    float4 g4 = *(const float4*)(gamma + fq * 4);
    float4 be4 = *(const float4*)(beta + fq * 4);

    float4 v = make_float4(a2.x + b4.x, a2.y + b4.y, a2.z + b4.z, a2.w + b4.w);
    float s = v.x + v.y + v.z + v.w;
    s += __shfl_xor(s, 1, 64);
    s += __shfl_xor(s, 2, 64);
    s += __shfl_xor(s, 4, 64);
    s += __shfl_xor(s, 8, 64);
    float mu = s * (1.0f / 64.0f);
    float4 d = make_float4(v.x - mu, v.y - mu, v.z - mu, v.w - mu);
    float q = d.x * d.x + d.y * d.y + d.z * d.z + d.w * d.w;
    q += __shfl_xor(q, 1, 64);
    q += __shfl_xor(q, 2, 64);
    q += __shfl_xor(q, 4, 64);
    q += __shfl_xor(q, 8, 64);
    float rstd = rsqrtf(q * (1.0f / 64.0f) + LN_EPS);
    float4 y = make_float4(fmaxf(fmaf(d.x * rstd, g4.x, be4.x), 0.f),
                           fmaxf(fmaf(d.y * rstd, g4.y, be4.y), 0.f),
                           fmaxf(fmaf(d.z * rstd, g4.z, be4.z), 0.f),
                           fmaxf(fmaf(d.w * rstd, g4.w, be4.w), 0.f));
    int row2 = base + wave;
    if (row2 < n && es == 0)
        *(float4*)(out + (size_t)row2 * DIM + fq * 4) = y;
}

// ---------------- launch ----------------

extern "C" void kernel_launch(void* const* d_in, const int* in_sizes, int n_in,
                              void* d_out, int out_size, void* d_ws, size_t ws_size,
                              hipStream_t stream) {
    const float* x      = (const float*)d_in[0];
    const int*   ei     = (const int*)  d_in[1];
    const float* Ws     = (const float*)d_in[2];
    const float* bs     = (const float*)d_in[3];
    const float* gammas = (const float*)d_in[4];
    const float* betas  = (const float*)d_in[5];
    float* out = (float*)d_out;

    int n = in_sizes[0] / DIM;
    int E = in_sizes[1] / 2;
    int n_layers = in_sizes[2] / (DIM * DIM);

    const int* srcp = ei;
    const int* dstp = ei + E;

    // ws layout (ints): deg[n] | rowstart[n] | dinv[n] | counter[2] |
    //                   rank[E] | csr[E] int2 | bufA[n*64] float
    int* deg      = (int*)d_ws;
    int* rowstart = deg + n;
    float* dinv   = (float*)(rowstart + n);
    int* counter  = (int*)(dinv + n);
    int* rank     = counter + 2;
    int2* csr     = (int2*)(rank + E);
    float* bufA   = (float*)(csr + E);

    int nb_n = (n + 255) / 256;
    int nb_e = (E + 255) / 256;

    k_zero   <<<nb_n, 256, 0, stream>>>(deg, counter, n);
    k_count  <<<nb_e, 256, 0, stream>>>(dstp, deg, rank, E);
    k_reserve<<<nb_n, 256, 0, stream>>>(deg, rowstart, dinv, counter, n);
    k_fill   <<<nb_e, 256, 0, stream>>>(srcp, dstp, dinv, rowstart, rank, csr, E);

    // Ping-pong layer outputs so xin never aliases the write target within
    // a dispatch (the gather reads arbitrary rows). Final layer lands in out.
    int nb_tile = (n + RPB - 1) / RPB;
    const float* src_buf = x;
    for (int i = 0; i < n_layers; i++) {
        float* dst = (((n_layers - 1 - i) & 1) == 0) ? out : bufA;
        k_layer<<<nb_tile, 256, 0, stream>>>(rowstart, deg, dinv, csr, src_buf,
                                             Ws + (size_t)i * DIM * DIM,
                                             bs + (size_t)i * DIM,
                                             gammas + (size_t)i * DIM,
                                             betas + (size_t)i * DIM, dst, n);
        src_buf = dst;
    }
}

// Round 12
// 232.317 us; speedup vs baseline: 1.2055x; 1.2055x over previous
//
#include <hip/hip_runtime.h>

#define DIM 64
#define LN_EPS 1e-5f
#define XS_STRIDE 68
#define RPB 16   // rows per block (verified spill-free round-9 structure)

// ---------------- helpers ----------------

__device__ __forceinline__ uint pack_bf2(float a, float b) {
    // round-to-nearest-even f32 -> bf16, pack two into one uint
    uint ba = __float_as_uint(a); ba = (ba + 0x7fffu + ((ba >> 16) & 1u)) >> 16;
    uint bb = __float_as_uint(b); bb = (bb + 0x7fffu + ((bb >> 16) & 1u)) >> 16;
    return ba | (bb << 16);
}

// ---------------- CSR build (once per call) ----------------

__global__ void k_zero(int* __restrict__ deg, int* __restrict__ counter, int n) {
    int i = blockIdx.x * blockDim.x + threadIdx.x;
    if (i < n) deg[i] = 0;
    if (i == 0) { counter[0] = 0; counter[1] = 0; }
}

// rank trick: the degree-count atomic ALREADY returns each edge's unique
// slot within its destination row. Save it; k_fill then needs no atomics.
__global__ void k_count(const int* __restrict__ dst, int* __restrict__ deg,
                        int* __restrict__ rank, int e_cnt) {
    int e = blockIdx.x * blockDim.x + threadIdx.x;
    if (e < e_cnt) rank[e] = atomicAdd(&deg[dst[e]], 1);
}

__global__ void k_reserve(const int* __restrict__ deg, int* __restrict__ rowstart,
                          float* __restrict__ dinv,
                          int* __restrict__ counter, int n) {
    int i = blockIdx.x * blockDim.x + threadIdx.x;
    if (i >= n) return;
    int d = deg[i];
    int s = atomicAdd(counter, d);
    rowstart[i] = s;
    dinv[i] = rsqrtf((float)(d + 1));
}

// atomic-free scatter: pos = rowstart[dst] + rank (unique, in-range)
__global__ void k_fill(const int* __restrict__ src, const int* __restrict__ dst,
                       const float* __restrict__ dinv,
                       const int* __restrict__ rowstart,
                       const int* __restrict__ rank,
                       int2* __restrict__ csr, int e_cnt) {
    int e = blockIdx.x * blockDim.x + threadIdx.x;
    if (e >= e_cnt) return;
    int s = src[e], d = dst[e];
    int pos = rowstart[d] + rank[e];
    float w = dinv[s] * dinv[d];
    csr[pos] = make_int2(s, __float_as_int(w));
}

// cast fp32 x -> bf16 rows (one float4 -> uint2 per thread)
__global__ void k_cast(const float4* __restrict__ in, uint2* __restrict__ outp,
                       int total) {
    int i = blockIdx.x * blockDim.x + threadIdx.x;
    if (i >= total) return;
    float4 v = in[i];
    uint2 o;
    o.x = pack_bf2(v.x, v.y);
    o.y = pack_bf2(v.z, v.w);
    outp[i] = o;
}

// ---------------- fused per-layer kernel ----------------
// ROUND-12: back to the verified RPB=16 spill-free structure (round 9/10),
// with BF16 intermediate storage. Round-11 evidence: tripling occupancy did
// NOT move the gather rate (2.45 TB/s pinned, FETCH ~115 MB vs 12.8 MB of
// source data -> per-XCD L2 miss traffic is the wall). The lever is BYTES:
// bf16 rows are 128 B (2 lines, was 4), and bf16 x (6.4 MB) nearly fits a
// 4 MiB per-XCD L2. Gather decodes uint2 -> 4 floats via shift/mask; all
// GEMM/LN math stays fp32; only storage is bf16. Final layer writes fp32.
// RACE NOTE: xin and out must NOT alias within one dispatch.
// kernel_launch ping-pongs: xbf -> bufB -> xbf -> out(fp32).
__global__ __launch_bounds__(256) void k_layer(const int* __restrict__ rowstart,
                                               const int* __restrict__ deg,
                                               const float* __restrict__ dinv,
                                               const int2* __restrict__ csr,
                                               const uint2* __restrict__ xin,  // bf16 rows
                                               const float* __restrict__ W,
                                               const float* __restrict__ b,
                                               const float* __restrict__ gamma,
                                               const float* __restrict__ beta,
                                               uint2* __restrict__ outb,   // bf16 out (layers 0,1)
                                               float* __restrict__ outf,   // fp32 out (last layer)
                                               int last, int n) {
    __shared__ float ws[DIM * DIM];
    __shared__ float xs[RPB * XS_STRIDE];
    int t = threadIdx.x;
    int base = blockIdx.x * RPB;

    {   // stage W: 1024 float4 across 256 threads; issued first so the loads
        // overlap aggregation latency.
        const float4* W4 = (const float4*)W;
        float4* ws4 = (float4*)ws;
#pragma unroll
        for (int i = 0; i < 4; i++) ws4[t + 256 * i] = W4[t + 256 * i];
    }

    // ---- phase 1: aggregation into xs ----
    int wave = t >> 6, lane = t & 63;
    int rs = lane >> 4;    // row slot 0..3
    int fq = lane & 15;    // feature quad 0..15 (4 bf16 = uint2 per lane)
    int lrow = wave * 4 + rs;          // local row 0..15
    int row = base + lrow;

    float4 acc = make_float4(0.f, 0.f, 0.f, 0.f);
    if (row < n) {
        int s0 = rowstart[row];
        int cnt = deg[row];
        int i = 0;
        for (; i + 4 <= cnt; i += 4) {
            int2 e0 = csr[s0 + i + 0];
            int2 e1 = csr[s0 + i + 1];
            int2 e2 = csr[s0 + i + 2];
            int2 e3 = csr[s0 + i + 3];
            uint2 u0 = xin[(size_t)e0.x * 16 + fq];
            uint2 u1 = xin[(size_t)e1.x * 16 + fq];
            uint2 u2 = xin[(size_t)e2.x * 16 + fq];
            uint2 u3 = xin[(size_t)e3.x * 16 + fq];
            float w0 = __int_as_float(e0.y);
            float w1 = __int_as_float(e1.y);
            float w2 = __int_as_float(e2.y);
            float w3 = __int_as_float(e3.y);
            acc.x = fmaf(w0, __uint_as_float(u0.x << 16), acc.x);
            acc.y = fmaf(w0, __uint_as_float(u0.x & 0xffff0000u), acc.y);
            acc.z = fmaf(w0, __uint_as_float(u0.y << 16), acc.z);
            acc.w = fmaf(w0, __uint_as_float(u0.y & 0xffff0000u), acc.w);
            acc.x = fmaf(w1, __uint_as_float(u1.x << 16), acc.x);
            acc.y = fmaf(w1, __uint_as_float(u1.x & 0xffff0000u), acc.y);
            acc.z = fmaf(w1, __uint_as_float(u1.y << 16), acc.z);
            acc.w = fmaf(w1, __uint_as_float(u1.y & 0xffff0000u), acc.w);
            acc.x = fmaf(w2, __uint_as_float(u2.x << 16), acc.x);
            acc.y = fmaf(w2, __uint_as_float(u2.x & 0xffff0000u), acc.y);
            acc.z = fmaf(w2, __uint_as_float(u2.y << 16), acc.z);
            acc.w = fmaf(w2, __uint_as_float(u2.y & 0xffff0000u), acc.w);
            acc.x = fmaf(w3, __uint_as_float(u3.x << 16), acc.x);
            acc.y = fmaf(w3, __uint_as_float(u3.x & 0xffff0000u), acc.y);
            acc.z = fmaf(w3, __uint_as_float(u3.y << 16), acc.z);
            acc.w = fmaf(w3, __uint_as_float(u3.y & 0xffff0000u), acc.w);
        }
        for (; i < cnt; i++) {
            int2 e0 = csr[s0 + i];
            uint2 u0 = xin[(size_t)e0.x * 16 + fq];
            float w0 = __int_as_float(e0.y);
            acc.x = fmaf(w0, __uint_as_float(u0.x << 16), acc.x);
            acc.y = fmaf(w0, __uint_as_float(u0.x & 0xffff0000u), acc.y);
            acc.z = fmaf(w0, __uint_as_float(u0.y << 16), acc.z);
            acc.w = fmaf(w0, __uint_as_float(u0.y & 0xffff0000u), acc.w);
        }
        // self-loop: dinv^2 * x[row]
        float di = dinv[row];
        float w = di * di;
        uint2 uv = xin[(size_t)row * 16 + fq];
        acc.x = fmaf(w, __uint_as_float(uv.x << 16), acc.x);
        acc.y = fmaf(w, __uint_as_float(uv.x & 0xffff0000u), acc.y);
        acc.z = fmaf(w, __uint_as_float(uv.y << 16), acc.z);
        acc.w = fmaf(w, __uint_as_float(uv.y & 0xffff0000u), acc.w);
    }
    *(float4*)(xs + lrow * XS_STRIDE + fq * 4) = acc;
    __syncthreads();

    // ---- phase 2: GEMM + bias + LN + relu (fp32) ----
    float4 a2 = make_float4(0.f, 0.f, 0.f, 0.f);
    for (int kc = 0; kc < 16; kc++) {
        float4 xv = *(const float4*)(xs + lrow * XS_STRIDE + kc * 4);
        float4 w0 = *(const float4*)(ws + (4 * kc + 0) * DIM + fq * 4);
        float4 w1 = *(const float4*)(ws + (4 * kc + 1) * DIM + fq * 4);
        float4 w2 = *(const float4*)(ws + (4 * kc + 2) * DIM + fq * 4);
        float4 w3 = *(const float4*)(ws + (4 * kc + 3) * DIM + fq * 4);
        a2.x = fmaf(xv.x, w0.x, a2.x);
        a2.y = fmaf(xv.x, w0.y, a2.y);
        a2.z = fmaf(xv.x, w0.z, a2.z);
        a2.w = fmaf(xv.x, w0.w, a2.w);
        a2.x = fmaf(xv.y, w1.x, a2.x);
        a2.y = fmaf(xv.y, w1.y, a2.y);
        a2.z = fmaf(xv.y, w1.z, a2.z);
        a2.w = fmaf(xv.y, w1.w, a2.w);
        a2.x = fmaf(xv.z, w2.x, a2.x);
        a2.y = fmaf(xv.z, w2.y, a2.y);
        a2.z = fmaf(xv.z, w2.z, a2.z);
        a2.w = fmaf(xv.z, w2.w, a2.w);
        a2.x = fmaf(xv.w, w3.x, a2.x);
        a2.y = fmaf(xv.w, w3.y, a2.y);
        a2.z = fmaf(xv.w, w3.z, a2.z);
        a2.w = fmaf(xv.w, w3.w, a2.w);
    }

    float4 b4 = *(const float4*)(b + fq * 4);
    float4 g4 = *(const float4*)(gamma + fq * 4);
    float4 be4 = *(const float4*)(beta + fq * 4);

    float4 v = make_float4(a2.x + b4.x, a2.y + b4.y, a2.z + b4.z, a2.w + b4.w);
    float s = v.x + v.y + v.z + v.w;
    s += __shfl_xor(s, 1, 64);
    s += __shfl_xor(s, 2, 64);
    s += __shfl_xor(s, 4, 64);
    s += __shfl_xor(s, 8, 64);
    float mu = s * (1.0f / 64.0f);
    float4 d = make_float4(v.x - mu, v.y - mu, v.z - mu, v.w - mu);
    float q = d.x * d.x + d.y * d.y + d.z * d.z + d.w * d.w;
    q += __shfl_xor(q, 1, 64);
    q += __shfl_xor(q, 2, 64);
    q += __shfl_xor(q, 4, 64);
    q += __shfl_xor(q, 8, 64);
    float rstd = rsqrtf(q * (1.0f / 64.0f) + LN_EPS);
    float4 y = make_float4(fmaxf(fmaf(d.x * rstd, g4.x, be4.x), 0.f),
                           fmaxf(fmaf(d.y * rstd, g4.y, be4.y), 0.f),
                           fmaxf(fmaf(d.z * rstd, g4.z, be4.z), 0.f),
                           fmaxf(fmaf(d.w * rstd, g4.w, be4.w), 0.f));
    if (row < n) {
        if (last) {
            *(float4*)(outf + (size_t)row * DIM + fq * 4) = y;
        } else {
            uint2 o;
            o.x = pack_bf2(y.x, y.y);
            o.y = pack_bf2(y.z, y.w);
            outb[(size_t)row * 16 + fq] = o;
        }
    }
}

// ---------------- launch ----------------

extern "C" void kernel_launch(void* const* d_in, const int* in_sizes, int n_in,
                              void* d_out, int out_size, void* d_ws, size_t ws_size,
                              hipStream_t stream) {
    const float* x      = (const float*)d_in[0];
    const int*   ei     = (const int*)  d_in[1];
    const float* Ws     = (const float*)d_in[2];
    const float* bs     = (const float*)d_in[3];
    const float* gammas = (const float*)d_in[4];
    const float* betas  = (const float*)d_in[5];
    float* out = (float*)d_out;

    int n = in_sizes[0] / DIM;
    int E = in_sizes[1] / 2;
    int n_layers = in_sizes[2] / (DIM * DIM);

    const int* srcp = ei;
    const int* dstp = ei + E;

    // ws layout (ints): deg[n] | rowstart[n] | dinv[n] | counter[2] |
    //                   rank[E] | csr[E] int2 | xbf[n*16 uint2] | bufB[n*16 uint2]
    int* deg      = (int*)d_ws;
    int* rowstart = deg + n;
    float* dinv   = (float*)(rowstart + n);
    int* counter  = (int*)(dinv + n);
    int* rank     = counter + 2;
    int2* csr     = (int2*)(rank + E);
    uint2* xbf    = (uint2*)(csr + E);        // bf16 [n][64]
    uint2* bufB   = xbf + (size_t)n * 16;     // bf16 [n][64]

    int nb_n = (n + 255) / 256;
    int nb_e = (E + 255) / 256;
    int nb_c = (n * 16 + 255) / 256;

    k_zero   <<<nb_n, 256, 0, stream>>>(deg, counter, n);
    k_count  <<<nb_e, 256, 0, stream>>>(dstp, deg, rank, E);
    k_reserve<<<nb_n, 256, 0, stream>>>(deg, rowstart, dinv, counter, n);
    k_fill   <<<nb_e, 256, 0, stream>>>(srcp, dstp, dinv, rowstart, rank, csr, E);
    k_cast   <<<nb_c, 256, 0, stream>>>((const float4*)x, xbf, n * 16);

    // Ping-pong bf16 buffers: xbf -> bufB -> xbf -> out (fp32, last layer).
    // xin never aliases the write target within a dispatch.
    int nb_tile = (n + RPB - 1) / RPB;
    const uint2* src_buf = xbf;
    for (int i = 0; i < n_layers; i++) {
        int last = (i == n_layers - 1);
        uint2* dstb = (src_buf == xbf) ? bufB : xbf;
        k_layer<<<nb_tile, 256, 0, stream>>>(rowstart, deg, dinv, csr, src_buf,
                                             Ws + (size_t)i * DIM * DIM,
                                             bs + (size_t)i * DIM,
                                             gammas + (size_t)i * DIM,
                                             betas + (size_t)i * DIM,
                                             dstb, out, last, n);
        src_buf = dstb;
    }
}

// Round 13
// 227.916 us; speedup vs baseline: 1.2287x; 1.0193x over previous
//
#include <hip/hip_runtime.h>

#define DIM 64
#define LN_EPS 1e-5f
#define XS_STRIDE 68
#define RPB 16   // rows per block (verified spill-free round-9 structure)

// ---------------- helpers ----------------

__device__ __forceinline__ uint pack_bf2(float a, float b) {
    // round-to-nearest-even f32 -> bf16, pack two into one uint
    uint ba = __float_as_uint(a); ba = (ba + 0x7fffu + ((ba >> 16) & 1u)) >> 16;
    uint bb = __float_as_uint(b); bb = (bb + 0x7fffu + ((bb >> 16) & 1u)) >> 16;
    return ba | (bb << 16);
}

// ---------------- CSR build (once per call) ----------------

__global__ void k_zero(int* __restrict__ deg, int* __restrict__ counter, int n) {
    int i = blockIdx.x * blockDim.x + threadIdx.x;
    if (i < n) deg[i] = 0;
    if (i == 0) { counter[0] = 0; counter[1] = 0; }
}

// rank trick: the degree-count atomic ALREADY returns each edge's unique
// slot within its destination row. Save it; k_fill then needs no atomics.
__global__ void k_count(const int* __restrict__ dst, int* __restrict__ deg,
                        int* __restrict__ rank, int e_cnt) {
    int e = blockIdx.x * blockDim.x + threadIdx.x;
    if (e < e_cnt) rank[e] = atomicAdd(&deg[dst[e]], 1);
}

__global__ void k_reserve(const int* __restrict__ deg, int* __restrict__ rowstart,
                          float* __restrict__ dinv,
                          int* __restrict__ counter, int n) {
    int i = blockIdx.x * blockDim.x + threadIdx.x;
    if (i >= n) return;
    int d = deg[i];
    int s = atomicAdd(counter, d);
    rowstart[i] = s;
    dinv[i] = rsqrtf((float)(d + 1));
}

// atomic-free scatter. PACKED 4-byte entry: (bf16(weight) << 16) | src.
// Valid because n = 50000 < 2^16. Decode: w = as_float(e & 0xffff0000)
// (bf16->f32 is exactly "bits in the high half"), src = e & 0xffff.
__global__ void k_fill(const int* __restrict__ src, const int* __restrict__ dst,
                       const float* __restrict__ dinv,
                       const int* __restrict__ rowstart,
                       const int* __restrict__ rank,
                       uint* __restrict__ csr, int e_cnt) {
    int e = blockIdx.x * blockDim.x + threadIdx.x;
    if (e >= e_cnt) return;
    int s = src[e], d = dst[e];
    int pos = rowstart[d] + rank[e];
    float w = dinv[s] * dinv[d];
    uint wu = __float_as_uint(w);
    uint wb = (wu + 0x7fffu + ((wu >> 16) & 1u)) & 0xffff0000u;  // rne bf16, high bits
    csr[pos] = wb | (uint)s;
}

// cast fp32 x -> bf16 rows (one float4 -> uint2 per thread)
__global__ void k_cast(const float4* __restrict__ in, uint2* __restrict__ outp,
                       int total) {
    int i = blockIdx.x * blockDim.x + threadIdx.x;
    if (i >= total) return;
    float4 v = in[i];
    uint2 o;
    o.x = pack_bf2(v.x, v.y);
    o.y = pack_bf2(v.z, v.w);
    outp[i] = o;
}

// ---------------- fused per-layer kernel ----------------
// ROUND-13: verified RPB=16 spill-free structure + bf16 feature storage
// (round 12, -20us) + two byte/issue-side levers:
//  * packed 4B csr entries (halved csr stream + single-dword decode)
//  * 8-deep edge unroll (serial batches per row: ~4 -> ~2; in-flight data
//    8x(uint+uint2) = 24 VGPR, LESS than the verified 4-deep fp32 version).
// Round-11 evidence stands: occupancy 27->74% moved nothing; the gather is
// L2-miss/transaction-bound -> only bytes and chain-length help.
// NO launch_bounds min-waves (rounds 7-8 spill trap).
// RACE NOTE: xin and out must NOT alias within one dispatch.
// kernel_launch ping-pongs: xbf -> bufB -> xbf -> out(fp32).
__global__ __launch_bounds__(256) void k_layer(const int* __restrict__ rowstart,
                                               const int* __restrict__ deg,
                                               const float* __restrict__ dinv,
                                               const uint* __restrict__ csr,
                                               const uint2* __restrict__ xin,  // bf16 rows
                                               const float* __restrict__ W,
                                               const float* __restrict__ b,
                                               const float* __restrict__ gamma,
                                               const float* __restrict__ beta,
                                               uint2* __restrict__ outb,   // bf16 out (layers 0,1)
                                               float* __restrict__ outf,   // fp32 out (last layer)
                                               int last, int n) {
    __shared__ float ws[DIM * DIM];
    __shared__ float xs[RPB * XS_STRIDE];
    int t = threadIdx.x;
    int base = blockIdx.x * RPB;

    {   // stage W: 1024 float4 across 256 threads; issued first so the loads
        // overlap aggregation latency.
        const float4* W4 = (const float4*)W;
        float4* ws4 = (float4*)ws;
#pragma unroll
        for (int i = 0; i < 4; i++) ws4[t + 256 * i] = W4[t + 256 * i];
    }

    // ---- phase 1: aggregation into xs ----
    int wave = t >> 6, lane = t & 63;
    int rs = lane >> 4;    // row slot 0..3
    int fq = lane & 15;    // feature quad 0..15 (4 bf16 = uint2 per lane)
    int lrow = wave * 4 + rs;          // local row 0..15
    int row = base + lrow;

    float4 acc = make_float4(0.f, 0.f, 0.f, 0.f);
    if (row < n) {
        int s0 = rowstart[row];
        int cnt = deg[row];
        int i = 0;
        // 8 edges in flight per iteration
        for (; i + 8 <= cnt; i += 8) {
            uint e0 = csr[s0 + i + 0];
            uint e1 = csr[s0 + i + 1];
            uint e2 = csr[s0 + i + 2];
            uint e3 = csr[s0 + i + 3];
            uint e4 = csr[s0 + i + 4];
            uint e5 = csr[s0 + i + 5];
            uint e6 = csr[s0 + i + 6];
            uint e7 = csr[s0 + i + 7];
            uint2 u0 = xin[(size_t)(e0 & 0xffffu) * 16 + fq];
            uint2 u1 = xin[(size_t)(e1 & 0xffffu) * 16 + fq];
            uint2 u2 = xin[(size_t)(e2 & 0xffffu) * 16 + fq];
            uint2 u3 = xin[(size_t)(e3 & 0xffffu) * 16 + fq];
            uint2 u4 = xin[(size_t)(e4 & 0xffffu) * 16 + fq];
            uint2 u5 = xin[(size_t)(e5 & 0xffffu) * 16 + fq];
            uint2 u6 = xin[(size_t)(e6 & 0xffffu) * 16 + fq];
            uint2 u7 = xin[(size_t)(e7 & 0xffffu) * 16 + fq];
            float w0 = __uint_as_float(e0 & 0xffff0000u);
            float w1 = __uint_as_float(e1 & 0xffff0000u);
            float w2 = __uint_as_float(e2 & 0xffff0000u);
            float w3 = __uint_as_float(e3 & 0xffff0000u);
            float w4 = __uint_as_float(e4 & 0xffff0000u);
            float w5 = __uint_as_float(e5 & 0xffff0000u);
            float w6 = __uint_as_float(e6 & 0xffff0000u);
            float w7 = __uint_as_float(e7 & 0xffff0000u);
            acc.x = fmaf(w0, __uint_as_float(u0.x << 16), acc.x);
            acc.y = fmaf(w0, __uint_as_float(u0.x & 0xffff0000u), acc.y);
            acc.z = fmaf(w0, __uint_as_float(u0.y << 16), acc.z);
            acc.w = fmaf(w0, __uint_as_float(u0.y & 0xffff0000u), acc.w);
            acc.x = fmaf(w1, __uint_as_float(u1.x << 16), acc.x);
            acc.y = fmaf(w1, __uint_as_float(u1.x & 0xffff0000u), acc.y);
            acc.z = fmaf(w1, __uint_as_float(u1.y << 16), acc.z);
            acc.w = fmaf(w1, __uint_as_float(u1.y & 0xffff0000u), acc.w);
            acc.x = fmaf(w2, __uint_as_float(u2.x << 16), acc.x);
            acc.y = fmaf(w2, __uint_as_float(u2.x & 0xffff0000u), acc.y);
            acc.z = fmaf(w2, __uint_as_float(u2.y << 16), acc.z);
            acc.w = fmaf(w2, __uint_as_float(u2.y & 0xffff0000u), acc.w);
            acc.x = fmaf(w3, __uint_as_float(u3.x << 16), acc.x);
            acc.y = fmaf(w3, __uint_as_float(u3.x & 0xffff0000u), acc.y);
            acc.z = fmaf(w3, __uint_as_float(u3.y << 16), acc.z);
            acc.w = fmaf(w3, __uint_as_float(u3.y & 0xffff0000u), acc.w);
            acc.x = fmaf(w4, __uint_as_float(u4.x << 16), acc.x);
            acc.y = fmaf(w4, __uint_as_float(u4.x & 0xffff0000u), acc.y);
            acc.z = fmaf(w4, __uint_as_float(u4.y << 16), acc.z);
            acc.w = fmaf(w4, __uint_as_float(u4.y & 0xffff0000u), acc.w);
            acc.x = fmaf(w5, __uint_as_float(u5.x << 16), acc.x);
            acc.y = fmaf(w5, __uint_as_float(u5.x & 0xffff0000u), acc.y);
            acc.z = fmaf(w5, __uint_as_float(u5.y << 16), acc.z);
            acc.w = fmaf(w5, __uint_as_float(u5.y & 0xffff0000u), acc.w);
            acc.x = fmaf(w6, __uint_as_float(u6.x << 16), acc.x);
            acc.y = fmaf(w6, __uint_as_float(u6.x & 0xffff0000u), acc.y);
            acc.z = fmaf(w6, __uint_as_float(u6.y << 16), acc.z);
            acc.w = fmaf(w6, __uint_as_float(u6.y & 0xffff0000u), acc.w);
            acc.x = fmaf(w7, __uint_as_float(u7.x << 16), acc.x);
            acc.y = fmaf(w7, __uint_as_float(u7.x & 0xffff0000u), acc.y);
            acc.z = fmaf(w7, __uint_as_float(u7.y << 16), acc.z);
            acc.w = fmaf(w7, __uint_as_float(u7.y & 0xffff0000u), acc.w);
        }
        if (i + 4 <= cnt) {
            uint e0 = csr[s0 + i + 0];
            uint e1 = csr[s0 + i + 1];
            uint e2 = csr[s0 + i + 2];
            uint e3 = csr[s0 + i + 3];
            uint2 u0 = xin[(size_t)(e0 & 0xffffu) * 16 + fq];
            uint2 u1 = xin[(size_t)(e1 & 0xffffu) * 16 + fq];
            uint2 u2 = xin[(size_t)(e2 & 0xffffu) * 16 + fq];
            uint2 u3 = xin[(size_t)(e3 & 0xffffu) * 16 + fq];
            float w0 = __uint_as_float(e0 & 0xffff0000u);
            float w1 = __uint_as_float(e1 & 0xffff0000u);
            float w2 = __uint_as_float(e2 & 0xffff0000u);
            float w3 = __uint_as_float(e3 & 0xffff0000u);
            acc.x = fmaf(w0, __uint_as_float(u0.x << 16), acc.x);
            acc.y = fmaf(w0, __uint_as_float(u0.x & 0xffff0000u), acc.y);
            acc.z = fmaf(w0, __uint_as_float(u0.y << 16), acc.z);
            acc.w = fmaf(w0, __uint_as_float(u0.y & 0xffff0000u), acc.w);
            acc.x = fmaf(w1, __uint_as_float(u1.x << 16), acc.x);
            acc.y = fmaf(w1, __uint_as_float(u1.x & 0xffff0000u), acc.y);
            acc.z = fmaf(w1, __uint_as_float(u1.y << 16), acc.z);
            acc.w = fmaf(w1, __uint_as_float(u1.y & 0xffff0000u), acc.w);
            acc.x = fmaf(w2, __uint_as_float(u2.x << 16), acc.x);
            acc.y = fmaf(w2, __uint_as_float(u2.x & 0xffff0000u), acc.y);
            acc.z = fmaf(w2, __uint_as_float(u2.y << 16), acc.z);
            acc.w = fmaf(w2, __uint_as_float(u2.y & 0xffff0000u), acc.w);
            acc.x = fmaf(w3, __uint_as_float(u3.x << 16), acc.x);
            acc.y = fmaf(w3, __uint_as_float(u3.x & 0xffff0000u), acc.y);
            acc.z = fmaf(w3, __uint_as_float(u3.y << 16), acc.z);
            acc.w = fmaf(w3, __uint_as_float(u3.y & 0xffff0000u), acc.w);
            i += 4;
        }
        for (; i < cnt; i++) {
            uint e0 = csr[s0 + i];
            uint2 u0 = xin[(size_t)(e0 & 0xffffu) * 16 + fq];
            float w0 = __uint_as_float(e0 & 0xffff0000u);
            acc.x = fmaf(w0, __uint_as_float(u0.x << 16), acc.x);
            acc.y = fmaf(w0, __uint_as_float(u0.x & 0xffff0000u), acc.y);
            acc.z = fmaf(w0, __uint_as_float(u0.y << 16), acc.z);
            acc.w = fmaf(w0, __uint_as_float(u0.y & 0xffff0000u), acc.w);
        }
        // self-loop: dinv^2 * x[row] (fp32 weight)
        float di = dinv[row];
        float w = di * di;
        uint2 uv = xin[(size_t)row * 16 + fq];
        acc.x = fmaf(w, __uint_as_float(uv.x << 16), acc.x);
        acc.y = fmaf(w, __uint_as_float(uv.x & 0xffff0000u), acc.y);
        acc.z = fmaf(w, __uint_as_float(uv.y << 16), acc.z);
        acc.w = fmaf(w, __uint_as_float(uv.y & 0xffff0000u), acc.w);
    }
    *(float4*)(xs + lrow * XS_STRIDE + fq * 4) = acc;
    __syncthreads();

    // ---- phase 2: GEMM + bias + LN + relu (fp32) ----
    float4 a2 = make_float4(0.f, 0.f, 0.f, 0.f);
    for (int kc = 0; kc < 16; kc++) {
        float4 xv = *(const float4*)(xs + lrow * XS_STRIDE + kc * 4);
        float4 w0 = *(const float4*)(ws + (4 * kc + 0) * DIM + fq * 4);
        float4 w1 = *(const float4*)(ws + (4 * kc + 1) * DIM + fq * 4);
        float4 w2 = *(const float4*)(ws + (4 * kc + 2) * DIM + fq * 4);
        float4 w3 = *(const float4*)(ws + (4 * kc + 3) * DIM + fq * 4);
        a2.x = fmaf(xv.x, w0.x, a2.x);
        a2.y = fmaf(xv.x, w0.y, a2.y);
        a2.z = fmaf(xv.x, w0.z, a2.z);
        a2.w = fmaf(xv.x, w0.w, a2.w);
        a2.x = fmaf(xv.y, w1.x, a2.x);
        a2.y = fmaf(xv.y, w1.y, a2.y);
        a2.z = fmaf(xv.y, w1.z, a2.z);
        a2.w = fmaf(xv.y, w1.w, a2.w);
        a2.x = fmaf(xv.z, w2.x, a2.x);
        a2.y = fmaf(xv.z, w2.y, a2.y);
        a2.z = fmaf(xv.z, w2.z, a2.z);
        a2.w = fmaf(xv.z, w2.w, a2.w);
        a2.x = fmaf(xv.w, w3.x, a2.x);
        a2.y = fmaf(xv.w, w3.y, a2.y);
        a2.z = fmaf(xv.w, w3.z, a2.z);
        a2.w = fmaf(xv.w, w3.w, a2.w);
    }

    float4 b4 = *(const float4*)(b + fq * 4);
    float4 g4 = *(const float4*)(gamma + fq * 4);
    float4 be4 = *(const float4*)(beta + fq * 4);

    float4 v = make_float4(a2.x + b4.x, a2.y + b4.y, a2.z + b4.z, a2.w + b4.w);
    float s = v.x + v.y + v.z + v.w;
    s += __shfl_xor(s, 1, 64);
    s += __shfl_xor(s, 2, 64);
    s += __shfl_xor(s, 4, 64);
    s += __shfl_xor(s, 8, 64);
    float mu = s * (1.0f / 64.0f);
    float4 d = make_float4(v.x - mu, v.y - mu, v.z - mu, v.w - mu);
    float q = d.x * d.x + d.y * d.y + d.z * d.z + d.w * d.w;
    q += __shfl_xor(q, 1, 64);
    q += __shfl_xor(q, 2, 64);
    q += __shfl_xor(q, 4, 64);
    q += __shfl_xor(q, 8, 64);
    float rstd = rsqrtf(q * (1.0f / 64.0f) + LN_EPS);
    float4 y = make_float4(fmaxf(fmaf(d.x * rstd, g4.x, be4.x), 0.f),
                           fmaxf(fmaf(d.y * rstd, g4.y, be4.y), 0.f),
                           fmaxf(fmaf(d.z * rstd, g4.z, be4.z), 0.f),
                           fmaxf(fmaf(d.w * rstd, g4.w, be4.w), 0.f));
    if (row < n) {
        if (last) {
            *(float4*)(outf + (size_t)row * DIM + fq * 4) = y;
        } else {
            uint2 o;
            o.x = pack_bf2(y.x, y.y);
            o.y = pack_bf2(y.z, y.w);
            outb[(size_t)row * 16 + fq] = o;
        }
    }
}

// ---------------- launch ----------------

extern "C" void kernel_launch(void* const* d_in, const int* in_sizes, int n_in,
                              void* d_out, int out_size, void* d_ws, size_t ws_size,
                              hipStream_t stream) {
    const float* x      = (const float*)d_in[0];
    const int*   ei     = (const int*)  d_in[1];
    const float* Ws     = (const float*)d_in[2];
    const float* bs     = (const float*)d_in[3];
    const float* gammas = (const float*)d_in[4];
    const float* betas  = (const float*)d_in[5];
    float* out = (float*)d_out;

    int n = in_sizes[0] / DIM;
    int E = in_sizes[1] / 2;
    int n_layers = in_sizes[2] / (DIM * DIM);

    const int* srcp = ei;
    const int* dstp = ei + E;

    // ws layout (ints): deg[n] | rowstart[n] | dinv[n] | counter[2] |
    //                   rank[E] | csr[E] uint | xbf[n*16 uint2] | bufB[n*16 uint2]
    int* deg      = (int*)d_ws;
    int* rowstart = deg + n;
    float* dinv   = (float*)(rowstart + n);
    int* counter  = (int*)(dinv + n);
    int* rank     = counter + 2;
    uint* csr     = (uint*)(rank + E);
    uint2* xbf    = (uint2*)(csr + E + (E & 1));   // keep 8B alignment
    uint2* bufB   = xbf + (size_t)n * 16;          // bf16 [n][64]

    int nb_n = (n + 255) / 256;
    int nb_e = (E + 255) / 256;
    int nb_c = (n * 16 + 255) / 256;

    k_zero   <<<nb_n, 256, 0, stream>>>(deg, counter, n);
    k_count  <<<nb_e, 256, 0, stream>>>(dstp, deg, rank, E);
    k_reserve<<<nb_n, 256, 0, stream>>>(deg, rowstart, dinv, counter, n);
    k_fill   <<<nb_e, 256, 0, stream>>>(srcp, dstp, dinv, rowstart, rank, csr, E);
    k_cast   <<<nb_c, 256, 0, stream>>>((const float4*)x, xbf, n * 16);

    // Ping-pong bf16 buffers: xbf -> bufB -> xbf -> out (fp32, last layer).
    // xin never aliases the write target within a dispatch.
    int nb_tile = (n + RPB - 1) / RPB;
    const uint2* src_buf = xbf;
    for (int i = 0; i < n_layers; i++) {
        int last = (i == n_layers - 1);
        uint2* dstb = (src_buf == xbf) ? bufB : xbf;
        k_layer<<<nb_tile, 256, 0, stream>>>(rowstart, deg, dinv, csr, src_buf,
                                             Ws + (size_t)i * DIM * DIM,
                                             bs + (size_t)i * DIM,
                                             gammas + (size_t)i * DIM,
                                             betas + (size_t)i * DIM,
                                             dstb, out, last, n);
        src_buf = dstb;
    }
}

// Round 14
// 223.247 us; speedup vs baseline: 1.2544x; 1.0209x over previous
//
#include <hip/hip_runtime.h>

#define DIM 64
#define LN_EPS 1e-5f
#define XS_STRIDE 68
#define RPB 16   // rows per block (verified spill-free round-9 structure)

// ---------------- helpers ----------------

__device__ __forceinline__ uint pack_bf2(float a, float b) {
    // round-to-nearest-even f32 -> bf16, pack two into one uint
    uint ba = __float_as_uint(a); ba = (ba + 0x7fffu + ((ba >> 16) & 1u)) >> 16;
    uint bb = __float_as_uint(b); bb = (bb + 0x7fffu + ((bb >> 16) & 1u)) >> 16;
    return ba | (bb << 16);
}

__device__ __forceinline__ uint pack_edge(float w, int s) {
    uint wu = __float_as_uint(w);
    return ((wu + 0x7fffu + ((wu >> 16) & 1u)) & 0xffff0000u) | (uint)s;
}

// ---------------- CSR build (once per call) ----------------

__global__ void k_zero(int* __restrict__ deg, int* __restrict__ counter, int n) {
    int i = blockIdx.x * blockDim.x + threadIdx.x;
    if (i < n) deg[i] = 0;
    if (i == 0) { counter[0] = 0; counter[1] = 0; }
}

// rank trick: the degree-count atomic ALREADY returns each edge's unique
// slot within its destination row. Save it; k_fill then needs no atomics.
// 2 edges per thread (int2 loads) to halve wave count / load instructions.
__global__ void k_count(const int* __restrict__ dst, int* __restrict__ deg,
                        int* __restrict__ rank, int e_cnt) {
    int e0 = (blockIdx.x * blockDim.x + threadIdx.x) * 2;
    if (e0 + 1 < e_cnt) {
        int2 d = *(const int2*)(dst + e0);
        int2 r;
        r.x = atomicAdd(&deg[d.x], 1);
        r.y = atomicAdd(&deg[d.y], 1);
        *(int2*)(rank + e0) = r;
    } else if (e0 < e_cnt) {
        rank[e0] = atomicAdd(&deg[dst[e0]], 1);
    }
}

// merged: per-node reserve (prefix via atomic) + fp32->bf16 cast of x.
// Disjoint ranges in one grid: i < n does reserve; i < total16 does cast.
__global__ void k_prep(const int* __restrict__ deg, int* __restrict__ rowstart,
                       float* __restrict__ dinv, int* __restrict__ counter, int n,
                       const float4* __restrict__ xin, uint2* __restrict__ xbf,
                       int total16) {
    int i = blockIdx.x * blockDim.x + threadIdx.x;
    if (i < n) {
        int d = deg[i];
        int s = atomicAdd(counter, d);
        rowstart[i] = s;
        dinv[i] = rsqrtf((float)(d + 1));
    }
    if (i < total16) {
        float4 v = xin[i];
        uint2 o;
        o.x = pack_bf2(v.x, v.y);
        o.y = pack_bf2(v.z, v.w);
        xbf[i] = o;
    }
}

// atomic-free scatter. PACKED 4-byte entry: (bf16(weight) << 16) | src
// (valid: n = 50000 < 2^16). 2 edges per thread.
__global__ void k_fill(const int* __restrict__ src, const int* __restrict__ dst,
                       const float* __restrict__ dinv,
                       const int* __restrict__ rowstart,
                       const int* __restrict__ rank,
                       uint* __restrict__ csr, int e_cnt) {
    int e0 = (blockIdx.x * blockDim.x + threadIdx.x) * 2;
    if (e0 + 1 < e_cnt) {
        int2 s = *(const int2*)(src + e0);
        int2 d = *(const int2*)(dst + e0);
        int2 r = *(const int2*)(rank + e0);
        csr[rowstart[d.x] + r.x] = pack_edge(dinv[s.x] * dinv[d.x], s.x);
        csr[rowstart[d.y] + r.y] = pack_edge(dinv[s.y] * dinv[d.y], s.y);
    } else if (e0 < e_cnt) {
        int s = src[e0], d = dst[e0];
        csr[rowstart[d] + rank[e0]] = pack_edge(dinv[s] * dinv[d], s);
    }
}

// ---------------- fused per-layer kernel ----------------
// VERIFIED structure (rounds 9-13): RPB=16, 256 threads, spill-free,
// bf16 feature storage + packed 4B csr. Gather is at the 8-XCD
// compulsory-miss floor (FETCH ~= 8 x buffer size; rate ~2.45 TB/s pinned
// across occupancy 27-74%) -> no further parallelism/depth levers.
// RACE NOTE: xin and out must NOT alias within one dispatch.
// kernel_launch ping-pongs: xbf -> bufB -> xbf -> out(fp32).
__global__ __launch_bounds__(256) void k_layer(const int* __restrict__ rowstart,
                                               const int* __restrict__ deg,
                                               const float* __restrict__ dinv,
                                               const uint* __restrict__ csr,
                                               const uint2* __restrict__ xin,  // bf16 rows
                                               const float* __restrict__ W,
                                               const float* __restrict__ b,
                                               const float* __restrict__ gamma,
                                               const float* __restrict__ beta,
                                               uint2* __restrict__ outb,   // bf16 out (layers 0,1)
                                               float* __restrict__ outf,   // fp32 out (last layer)
                                               int last, int n) {
    __shared__ float ws[DIM * DIM];
    __shared__ float xs[RPB * XS_STRIDE];
    int t = threadIdx.x;
    int base = blockIdx.x * RPB;

    {   // stage W: 1024 float4 across 256 threads; issued first so the loads
        // overlap aggregation latency.
        const float4* W4 = (const float4*)W;
        float4* ws4 = (float4*)ws;
#pragma unroll
        for (int i = 0; i < 4; i++) ws4[t + 256 * i] = W4[t + 256 * i];
    }

    // ---- phase 1: aggregation into xs ----
    int wave = t >> 6, lane = t & 63;
    int rs = lane >> 4;    // row slot 0..3
    int fq = lane & 15;    // feature quad 0..15 (4 bf16 = uint2 per lane)
    int lrow = wave * 4 + rs;          // local row 0..15
    int row = base + lrow;

    float4 acc = make_float4(0.f, 0.f, 0.f, 0.f);
    if (row < n) {
        int s0 = rowstart[row];
        int cnt = deg[row];
        int i = 0;
        // 8 edges in flight per iteration
        for (; i + 8 <= cnt; i += 8) {
            uint e0 = csr[s0 + i + 0];
            uint e1 = csr[s0 + i + 1];
            uint e2 = csr[s0 + i + 2];
            uint e3 = csr[s0 + i + 3];
            uint e4 = csr[s0 + i + 4];
            uint e5 = csr[s0 + i + 5];
            uint e6 = csr[s0 + i + 6];
            uint e7 = csr[s0 + i + 7];
            uint2 u0 = xin[(size_t)(e0 & 0xffffu) * 16 + fq];
            uint2 u1 = xin[(size_t)(e1 & 0xffffu) * 16 + fq];
            uint2 u2 = xin[(size_t)(e2 & 0xffffu) * 16 + fq];
            uint2 u3 = xin[(size_t)(e3 & 0xffffu) * 16 + fq];
            uint2 u4 = xin[(size_t)(e4 & 0xffffu) * 16 + fq];
            uint2 u5 = xin[(size_t)(e5 & 0xffffu) * 16 + fq];
            uint2 u6 = xin[(size_t)(e6 & 0xffffu) * 16 + fq];
            uint2 u7 = xin[(size_t)(e7 & 0xffffu) * 16 + fq];
            float w0 = __uint_as_float(e0 & 0xffff0000u);
            float w1 = __uint_as_float(e1 & 0xffff0000u);
            float w2 = __uint_as_float(e2 & 0xffff0000u);
            float w3 = __uint_as_float(e3 & 0xffff0000u);
            float w4 = __uint_as_float(e4 & 0xffff0000u);
            float w5 = __uint_as_float(e5 & 0xffff0000u);
            float w6 = __uint_as_float(e6 & 0xffff0000u);
            float w7 = __uint_as_float(e7 & 0xffff0000u);
            acc.x = fmaf(w0, __uint_as_float(u0.x << 16), acc.x);
            acc.y = fmaf(w0, __uint_as_float(u0.x & 0xffff0000u), acc.y);
            acc.z = fmaf(w0, __uint_as_float(u0.y << 16), acc.z);
            acc.w = fmaf(w0, __uint_as_float(u0.y & 0xffff0000u), acc.w);
            acc.x = fmaf(w1, __uint_as_float(u1.x << 16), acc.x);
            acc.y = fmaf(w1, __uint_as_float(u1.x & 0xffff0000u), acc.y);
            acc.z = fmaf(w1, __uint_as_float(u1.y << 16), acc.z);
            acc.w = fmaf(w1, __uint_as_float(u1.y & 0xffff0000u), acc.w);
            acc.x = fmaf(w2, __uint_as_float(u2.x << 16), acc.x);
            acc.y = fmaf(w2, __uint_as_float(u2.x & 0xffff0000u), acc.y);
            acc.z = fmaf(w2, __uint_as_float(u2.y << 16), acc.z);
            acc.w = fmaf(w2, __uint_as_float(u2.y & 0xffff0000u), acc.w);
            acc.x = fmaf(w3, __uint_as_float(u3.x << 16), acc.x);
            acc.y = fmaf(w3, __uint_as_float(u3.x & 0xffff0000u), acc.y);
            acc.z = fmaf(w3, __uint_as_float(u3.y << 16), acc.z);
            acc.w = fmaf(w3, __uint_as_float(u3.y & 0xffff0000u), acc.w);
            acc.x = fmaf(w4, __uint_as_float(u4.x << 16), acc.x);
            acc.y = fmaf(w4, __uint_as_float(u4.x & 0xffff0000u), acc.y);
            acc.z = fmaf(w4, __uint_as_float(u4.y << 16), acc.z);
            acc.w = fmaf(w4, __uint_as_float(u4.y & 0xffff0000u), acc.w);
            acc.x = fmaf(w5, __uint_as_float(u5.x << 16), acc.x);
            acc.y = fmaf(w5, __uint_as_float(u5.x & 0xffff0000u), acc.y);
            acc.z = fmaf(w5, __uint_as_float(u5.y << 16), acc.z);
            acc.w = fmaf(w5, __uint_as_float(u5.y & 0xffff0000u), acc.w);
            acc.x = fmaf(w6, __uint_as_float(u6.x << 16), acc.x);
            acc.y = fmaf(w6, __uint_as_float(u6.x & 0xffff0000u), acc.y);
            acc.z = fmaf(w6, __uint_as_float(u6.y << 16), acc.z);
            acc.w = fmaf(w6, __uint_as_float(u6.y & 0xffff0000u), acc.w);
            acc.x = fmaf(w7, __uint_as_float(u7.x << 16), acc.x);
            acc.y = fmaf(w7, __uint_as_float(u7.x & 0xffff0000u), acc.y);
            acc.z = fmaf(w7, __uint_as_float(u7.y << 16), acc.z);
            acc.w = fmaf(w7, __uint_as_float(u7.y & 0xffff0000u), acc.w);
        }
        if (i + 4 <= cnt) {
            uint e0 = csr[s0 + i + 0];
            uint e1 = csr[s0 + i + 1];
            uint e2 = csr[s0 + i + 2];
            uint e3 = csr[s0 + i + 3];
            uint2 u0 = xin[(size_t)(e0 & 0xffffu) * 16 + fq];
            uint2 u1 = xin[(size_t)(e1 & 0xffffu) * 16 + fq];
            uint2 u2 = xin[(size_t)(e2 & 0xffffu) * 16 + fq];
            uint2 u3 = xin[(size_t)(e3 & 0xffffu) * 16 + fq];
            float w0 = __uint_as_float(e0 & 0xffff0000u);
            float w1 = __uint_as_float(e1 & 0xffff0000u);
            float w2 = __uint_as_float(e2 & 0xffff0000u);
            float w3 = __uint_as_float(e3 & 0xffff0000u);
            acc.x = fmaf(w0, __uint_as_float(u0.x << 16), acc.x);
            acc.y = fmaf(w0, __uint_as_float(u0.x & 0xffff0000u), acc.y);
            acc.z = fmaf(w0, __uint_as_float(u0.y << 16), acc.z);
            acc.w = fmaf(w0, __uint_as_float(u0.y & 0xffff0000u), acc.w);
            acc.x = fmaf(w1, __uint_as_float(u1.x << 16), acc.x);
            acc.y = fmaf(w1, __uint_as_float(u1.x & 0xffff0000u), acc.y);
            acc.z = fmaf(w1, __uint_as_float(u1.y << 16), acc.z);
            acc.w = fmaf(w1, __uint_as_float(u1.y & 0xffff0000u), acc.w);
            acc.x = fmaf(w2, __uint_as_float(u2.x << 16), acc.x);
            acc.y = fmaf(w2, __uint_as_float(u2.x & 0xffff0000u), acc.y);
            acc.z = fmaf(w2, __uint_as_float(u2.y << 16), acc.z);
            acc.w = fmaf(w2, __uint_as_float(u2.y & 0xffff0000u), acc.w);
            acc.x = fmaf(w3, __uint_as_float(u3.x << 16), acc.x);
            acc.y = fmaf(w3, __uint_as_float(u3.x & 0xffff0000u), acc.y);
            acc.z = fmaf(w3, __uint_as_float(u3.y << 16), acc.z);
            acc.w = fmaf(w3, __uint_as_float(u3.y & 0xffff0000u), acc.w);
            i += 4;
        }
        for (; i < cnt; i++) {
            uint e0 = csr[s0 + i];
            uint2 u0 = xin[(size_t)(e0 & 0xffffu) * 16 + fq];
            float w0 = __uint_as_float(e0 & 0xffff0000u);
            acc.x = fmaf(w0, __uint_as_float(u0.x << 16), acc.x);
            acc.y = fmaf(w0, __uint_as_float(u0.x & 0xffff0000u), acc.y);
            acc.z = fmaf(w0, __uint_as_float(u0.y << 16), acc.z);
            acc.w = fmaf(w0, __uint_as_float(u0.y & 0xffff0000u), acc.w);
        }
        // self-loop: dinv^2 * x[row] (fp32 weight)
        float di = dinv[row];
        float w = di * di;
        uint2 uv = xin[(size_t)row * 16 + fq];
        acc.x = fmaf(w, __uint_as_float(uv.x << 16), acc.x);
        acc.y = fmaf(w, __uint_as_float(uv.x & 0xffff0000u), acc.y);
        acc.z = fmaf(w, __uint_as_float(uv.y << 16), acc.z);
        acc.w = fmaf(w, __uint_as_float(uv.y & 0xffff0000u), acc.w);
    }
    *(float4*)(xs + lrow * XS_STRIDE + fq * 4) = acc;
    __syncthreads();

    // ---- phase 2: GEMM + bias + LN + relu (fp32) ----
    float4 a2 = make_float4(0.f, 0.f, 0.f, 0.f);
    for (int kc = 0; kc < 16; kc++) {
        float4 xv = *(const float4*)(xs + lrow * XS_STRIDE + kc * 4);
        float4 w0 = *(const float4*)(ws + (4 * kc + 0) * DIM + fq * 4);
        float4 w1 = *(const float4*)(ws + (4 * kc + 1) * DIM + fq * 4);
        float4 w2 = *(const float4*)(ws + (4 * kc + 2) * DIM + fq * 4);
        float4 w3 = *(const float4*)(ws + (4 * kc + 3) * DIM + fq * 4);
        a2.x = fmaf(xv.x, w0.x, a2.x);
        a2.y = fmaf(xv.x, w0.y, a2.y);
        a2.z = fmaf(xv.x, w0.z, a2.z);
        a2.w = fmaf(xv.x, w0.w, a2.w);
        a2.x = fmaf(xv.y, w1.x, a2.x);
        a2.y = fmaf(xv.y, w1.y, a2.y);
        a2.z = fmaf(xv.y, w1.z, a2.z);
        a2.w = fmaf(xv.y, w1.w, a2.w);
        a2.x = fmaf(xv.z, w2.x, a2.x);
        a2.y = fmaf(xv.z, w2.y, a2.y);
        a2.z = fmaf(xv.z, w2.z, a2.z);
        a2.w = fmaf(xv.z, w2.w, a2.w);
        a2.x = fmaf(xv.w, w3.x, a2.x);
        a2.y = fmaf(xv.w, w3.y, a2.y);
        a2.z = fmaf(xv.w, w3.z, a2.z);
        a2.w = fmaf(xv.w, w3.w, a2.w);
    }

    float4 b4 = *(const float4*)(b + fq * 4);
    float4 g4 = *(const float4*)(gamma + fq * 4);
    float4 be4 = *(const float4*)(beta + fq * 4);

    float4 v = make_float4(a2.x + b4.x, a2.y + b4.y, a2.z + b4.z, a2.w + b4.w);
    float s = v.x + v.y + v.z + v.w;
    s += __shfl_xor(s, 1, 64);
    s += __shfl_xor(s, 2, 64);
    s += __shfl_xor(s, 4, 64);
    s += __shfl_xor(s, 8, 64);
    float mu = s * (1.0f / 64.0f);
    float4 d = make_float4(v.x - mu, v.y - mu, v.z - mu, v.w - mu);
    float q = d.x * d.x + d.y * d.y + d.z * d.z + d.w * d.w;
    q += __shfl_xor(q, 1, 64);
    q += __shfl_xor(q, 2, 64);
    q += __shfl_xor(q, 4, 64);
    q += __shfl_xor(q, 8, 64);
    float rstd = rsqrtf(q * (1.0f / 64.0f) + LN_EPS);
    float4 y = make_float4(fmaxf(fmaf(d.x * rstd, g4.x, be4.x), 0.f),
                           fmaxf(fmaf(d.y * rstd, g4.y, be4.y), 0.f),
                           fmaxf(fmaf(d.z * rstd, g4.z, be4.z), 0.f),
                           fmaxf(fmaf(d.w * rstd, g4.w, be4.w), 0.f));
    if (row < n) {
        if (last) {
            *(float4*)(outf + (size_t)row * DIM + fq * 4) = y;
        } else {
            uint2 o;
            o.x = pack_bf2(y.x, y.y);
            o.y = pack_bf2(y.z, y.w);
            outb[(size_t)row * 16 + fq] = o;
        }
    }
}

// ---------------- launch ----------------

extern "C" void kernel_launch(void* const* d_in, const int* in_sizes, int n_in,
                              void* d_out, int out_size, void* d_ws, size_t ws_size,
                              hipStream_t stream) {
    const float* x      = (const float*)d_in[0];
    const int*   ei     = (const int*)  d_in[1];
    const float* Ws     = (const float*)d_in[2];
    const float* bs     = (const float*)d_in[3];
    const float* gammas = (const float*)d_in[4];
    const float* betas  = (const float*)d_in[5];
    float* out = (float*)d_out;

    int n = in_sizes[0] / DIM;
    int E = in_sizes[1] / 2;
    int n_layers = in_sizes[2] / (DIM * DIM);

    const int* srcp = ei;
    const int* dstp = ei + E;

    // ws layout (ints): deg[n] | rowstart[n] | dinv[n] | counter[2] |
    //                   rank[E] | csr[E] uint | xbf[n*16 uint2] | bufB[n*16 uint2]
    int* deg      = (int*)d_ws;
    int* rowstart = deg + n;
    float* dinv   = (float*)(rowstart + n);
    int* counter  = (int*)(dinv + n);
    int* rank     = counter + 2;
    uint* csr     = (uint*)(rank + E);
    uint2* xbf    = (uint2*)(csr + E + (E & 1));   // keep 8B alignment
    uint2* bufB   = xbf + (size_t)n * 16;          // bf16 [n][64]

    int nb_n  = (n + 255) / 256;
    int nb_e2 = (E / 2 + 256) / 256;               // 2 edges per thread
    int nb_c  = (n * 16 + 255) / 256;              // covers both prep ranges

    k_zero <<<nb_n, 256, 0, stream>>>(deg, counter, n);
    k_count<<<nb_e2, 256, 0, stream>>>(dstp, deg, rank, E);
    k_prep <<<nb_c, 256, 0, stream>>>(deg, rowstart, dinv, counter, n,
                                      (const float4*)x, xbf, n * 16);
    k_fill <<<nb_e2, 256, 0, stream>>>(srcp, dstp, dinv, rowstart, rank, csr, E);

    // Ping-pong bf16 buffers: xbf -> bufB -> xbf -> out (fp32, last layer).
    // xin never aliases the write target within a dispatch.
    int nb_tile = (n + RPB - 1) / RPB;
    const uint2* src_buf = xbf;
    for (int i = 0; i < n_layers; i++) {
        int last = (i == n_layers - 1);
        uint2* dstb = (src_buf == xbf) ? bufB : xbf;
        k_layer<<<nb_tile, 256, 0, stream>>>(rowstart, deg, dinv, csr, src_buf,
                                             Ws + (size_t)i * DIM * DIM,
                                             bs + (size_t)i * DIM,
                                             gammas + (size_t)i * DIM,
                                             betas + (size_t)i * DIM,
                                             dstb, out, last, n);
        src_buf = dstb;
    }
}